// Round 5
// baseline (377.028 us; speedup 1.0000x reference)
//
#include <hip/hip_runtime.h>
#include <hip/hip_cooperative_groups.h>

namespace cg = cooperative_groups;

typedef float v4f __attribute__((ext_vector_type(4)));

#define NB   32     // batch
#define NT   8      // timesteps
#define NC   128    // channels
#define NQ   256    // float4s per (H*W)=1024 plane
#define CRED 32     // C/red
#define PADI 32     // ints of padding per arrival counter (128 B line)

// Cross-block state in device globals. ALL cross-block traffic goes through
// relaxed agent-scope atomics (sc0/sc1 -> LLC-direct, bypassing L1/L2), so no
// release/acquire fences are needed anywhere -> no buffer_wbl2 / buffer_inv
// cache-maintenance storms (the R2/R4 ~40 us/step stall).
__device__ int                g_arrive[NB * PADI];      // per-batch arrival counters
__device__ unsigned long long g_xsum[2 * NB * NC];      // double-buffered mean bits
__device__ float              g_tau[NB];                // fallback path
__device__ float              g_mem[NB * NC * NQ * 4];  // fallback path

__global__ __launch_bounds__(256)
void lif_init() {
    int i = threadIdx.x + blockIdx.x * blockDim.x;
    if (i < NB * PADI) g_arrive[i] = 0;
}

// ---------------------------------------------------------------------------
// Path A: single persistent kernel (cooperative launch for co-residency).
// 1024 blocks (one per (b, 4-channel group)), 256 threads; mem in registers.
// Per step: fused fma/spike/reset/store + plane-mean publish (LLC atomics),
// per-batch 32-arrival barrier (relaxed atomics, NO fences), then each block
// redundantly computes its batch's 128->32->1 MLP for the next tau.
// ---------------------------------------------------------------------------
__global__ __launch_bounds__(256, 4)
void dynamic_lif_coop(const float* __restrict__ x,
                      const float* __restrict__ w1,
                      const float* __restrict__ b1,
                      const float* __restrict__ w2,
                      const float* __restrict__ b2,
                      float* __restrict__ out)
{
    const int bid = blockIdx.x;          // 0..1023
    const int b   = bid >> 5;            // batch
    const int c0  = (bid & 31) << 2;     // first of 4 channels
    const int tid = threadIdx.x;
    const int wv  = tid >> 6;
    const int ln  = tid & 63;

    __shared__ double s_part[4][4];
    __shared__ float  s_tau;

    const v4f* __restrict__ x4 = (const v4f*)x;
    v4f* __restrict__ o4       = (v4f*)out;

    v4f mem[4];
    #pragma unroll
    for (int p = 0; p < 4; ++p) mem[p] = (v4f){0.f, 0.f, 0.f, 0.f};

    float tau = 0.5f;                    // TAU0

    v4f xv[4];
    #pragma unroll
    for (int p = 0; p < 4; ++p)
        xv[p] = __builtin_nontemporal_load(x4 + ((b * NT + 0) * NC + c0 + p) * NQ + tid);

    for (int t = 0; t < NT; ++t) {
        double psum[4];
        #pragma unroll
        for (int p = 0; p < 4; ++p) {
            v4f m = mem[p];
            m.x = fmaf(m.x, tau, xv[p].x);
            m.y = fmaf(m.y, tau, xv[p].y);
            m.z = fmaf(m.z, tau, xv[p].z);
            m.w = fmaf(m.w, tau, xv[p].w);
            psum[p] = ((double)m.x + (double)m.y) + ((double)m.z + (double)m.w);
            v4f sp;
            sp.x = (m.x > 1.0f) ? 1.0f : 0.0f;   // zif(mem-1): exact (Sterbenz)
            sp.y = (m.y > 1.0f) ? 1.0f : 0.0f;
            sp.z = (m.z > 1.0f) ? 1.0f : 0.0f;
            sp.w = (m.w > 1.0f) ? 1.0f : 0.0f;
            __builtin_nontemporal_store(sp, o4 + ((b * NT + t) * NC + c0 + p) * NQ + tid);
            m.x = (m.x > 1.0f) ? 0.0f : m.x;     // (1-spike)*mem
            m.y = (m.y > 1.0f) ? 0.0f : m.y;
            m.z = (m.z > 1.0f) ? 0.0f : m.z;
            m.w = (m.w > 1.0f) ? 0.0f : m.w;
            mem[p] = m;
        }

        // prefetch next x so the loads fly across the reduce + barrier
        if (t + 1 < NT) {
            #pragma unroll
            for (int p = 0; p < 4; ++p)
                xv[p] = __builtin_nontemporal_load(
                    x4 + ((b * NT + (t + 1)) * NC + c0 + p) * NQ + tid);
        }

        #pragma unroll
        for (int p = 0; p < 4; ++p) {
            double s = psum[p];
            #pragma unroll
            for (int off = 32; off > 0; off >>= 1) s += __shfl_down(s, off);
            if (ln == 0) s_part[p][wv] = s;
        }
        __syncthreads();
        if (tid < 4) {
            double s = (s_part[tid][0] + s_part[tid][1]) +
                       (s_part[tid][2] + s_part[tid][3]);
            double mean = s * (1.0 / 1024.0);
            unsigned long long bits = __double_as_longlong(mean);
            // LLC-direct publish: no fence needed, bypasses L1/L2
            __hip_atomic_store(&g_xsum[(t & 1) * (NB * NC) + b * NC + c0 + tid],
                               bits, __ATOMIC_RELAXED, __HIP_MEMORY_SCOPE_AGENT);
        }
        __syncthreads();   // s_waitcnt vmcnt(0): xsum stores committed at LLC

        if (t == NT - 1) break;

        // ---- per-batch barrier: relaxed LLC atomics only, zero fences ----
        if (tid == 0) {
            __hip_atomic_fetch_add(&g_arrive[b * PADI], 1,
                                   __ATOMIC_RELAXED, __HIP_MEMORY_SCOPE_AGENT);
            const int target = 32 * (t + 1);     // monotonic; init kernel zeroes
            while (__hip_atomic_load(&g_arrive[b * PADI],
                                     __ATOMIC_RELAXED, __HIP_MEMORY_SCOPE_AGENT) < target)
                __builtin_amdgcn_s_sleep(2);
        }
        __syncthreads();

        // tiny MLP (128->32->1), recomputed per block for its own batch.
        // xm via LLC-direct atomic loads (cannot be stale); w1 stays cached.
        double e = 0.0;
        if (tid < CRED) {
            const unsigned long long* __restrict__ xm =
                g_xsum + (t & 1) * (NB * NC) + b * NC;
            const float* __restrict__ w1r = w1 + tid * NC;
            double acc = (double)b1[tid];
            #pragma unroll 8
            for (int cc = 0; cc < NC; ++cc) {
                unsigned long long mb =
                    __hip_atomic_load(&xm[cc], __ATOMIC_RELAXED,
                                      __HIP_MEMORY_SCOPE_AGENT);
                acc += __longlong_as_double(mb) * (double)w1r[cc];
            }
            double emb = acc > 0.0 ? acc : 0.0;
            e = emb * (double)w2[tid];
        }
        #pragma unroll
        for (int off = 32; off > 0; off >>= 1) e += __shfl_down(e, off);
        if (tid == 0) {
            double z = e + (double)b2[0];
            s_tau = (float)(1.0 / (1.0 + exp(-z)));
        }
        __syncthreads();
        tau = s_tau;
    }
}

// ---------------------------------------------------------------------------
// Path B (fallback, standard launches): per-step kernel + MLP kernel, mem in
// g_mem. Identical per-element arithmetic.
// ---------------------------------------------------------------------------
__global__ __launch_bounds__(256)
void lif_step(const float* __restrict__ x, float* __restrict__ out, int t)
{
    const int bid = blockIdx.x;
    const int b   = bid >> 5;
    const int c0  = (bid & 31) << 2;
    const int tid = threadIdx.x;
    const int wv  = tid >> 6;
    const int ln  = tid & 63;

    __shared__ double s_part[4][4];

    const float tau = (t == 0) ? 0.5f : g_tau[b];
    const v4f* __restrict__ x4 = (const v4f*)x;
    v4f* __restrict__ o4       = (v4f*)out;
    v4f* __restrict__ m4       = (v4f*)g_mem;

    double psum[4];
    #pragma unroll
    for (int p = 0; p < 4; ++p) {
        const int mi = (b * NC + c0 + p) * NQ + tid;
        const int oi = ((b * NT + t) * NC + c0 + p) * NQ + tid;
        v4f m = (t == 0) ? (v4f){0.f, 0.f, 0.f, 0.f} : m4[mi];
        v4f xv = __builtin_nontemporal_load(x4 + oi);
        m.x = fmaf(m.x, tau, xv.x);
        m.y = fmaf(m.y, tau, xv.y);
        m.z = fmaf(m.z, tau, xv.z);
        m.w = fmaf(m.w, tau, xv.w);
        psum[p] = ((double)m.x + (double)m.y) + ((double)m.z + (double)m.w);
        v4f sp;
        sp.x = (m.x > 1.0f) ? 1.0f : 0.0f;
        sp.y = (m.y > 1.0f) ? 1.0f : 0.0f;
        sp.z = (m.z > 1.0f) ? 1.0f : 0.0f;
        sp.w = (m.w > 1.0f) ? 1.0f : 0.0f;
        __builtin_nontemporal_store(sp, o4 + oi);
        m.x = (m.x > 1.0f) ? 0.0f : m.x;
        m.y = (m.y > 1.0f) ? 0.0f : m.y;
        m.z = (m.z > 1.0f) ? 0.0f : m.z;
        m.w = (m.w > 1.0f) ? 0.0f : m.w;
        m4[mi] = m;
    }

    #pragma unroll
    for (int p = 0; p < 4; ++p) {
        double s = psum[p];
        #pragma unroll
        for (int off = 32; off > 0; off >>= 1) s += __shfl_down(s, off);
        if (ln == 0) s_part[p][wv] = s;
    }
    __syncthreads();
    if (tid < 4) {
        double s = (s_part[tid][0] + s_part[tid][1]) +
                   (s_part[tid][2] + s_part[tid][3]);
        g_xsum[b * NC + c0 + tid] = __double_as_longlong(s * (1.0 / 1024.0));
    }
}

__global__ __launch_bounds__(64)
void lif_mlp(const float* __restrict__ w1, const float* __restrict__ b1,
             const float* __restrict__ w2, const float* __restrict__ b2)
{
    const int b  = blockIdx.x;
    const int ln = threadIdx.x;
    double e = 0.0;
    if (ln < CRED) {
        const unsigned long long* __restrict__ xm = g_xsum + b * NC;
        const float* __restrict__ w1r = w1 + ln * NC;
        double acc = (double)b1[ln];
        #pragma unroll 8
        for (int cc = 0; cc < NC; ++cc)
            acc += __longlong_as_double(xm[cc]) * (double)w1r[cc];
        double emb = acc > 0.0 ? acc : 0.0;
        e = emb * (double)w2[ln];
    }
    #pragma unroll
    for (int off = 32; off > 0; off >>= 1) e += __shfl_down(e, off);
    if (ln == 0) {
        double z = e + (double)b2[0];
        g_tau[b] = (float)(1.0 / (1.0 + exp(-z)));
    }
}

extern "C" void kernel_launch(void* const* d_in, const int* in_sizes, int n_in,
                              void* d_out, int out_size, void* d_ws, size_t ws_size,
                              hipStream_t stream) {
    const float* x  = (const float*)d_in[0];
    const float* w1 = (const float*)d_in[1];
    const float* b1 = (const float*)d_in[2];
    const float* w2 = (const float*)d_in[3];
    const float* b2 = (const float*)d_in[4];
    float* out      = (float*)d_out;

    int dev = 0;
    (void)hipGetDevice(&dev);
    int numCU = 0;
    (void)hipDeviceGetAttribute(&numCU, hipDeviceAttributeMultiprocessorCount, dev);
    int perCU = 0;
    hipError_t qe = hipOccupancyMaxActiveBlocksPerMultiprocessor(&perCU, dynamic_lif_coop, 256, 0);

    bool coop = (qe == hipSuccess) && numCU > 0 &&
                ((long)perCU * (long)numCU >= (long)(NB * NC / 4));
    if (coop) {
        hipLaunchKernelGGL(lif_init, dim3((NB * PADI + 255) / 256), dim3(256),
                           0, stream);
        void* args[6] = { (void*)&x, (void*)&w1, (void*)&b1,
                          (void*)&w2, (void*)&b2, (void*)&out };
        hipError_t le = hipLaunchCooperativeKernel((void*)dynamic_lif_coop,
                                                   dim3(NB * NC / 4), dim3(256),
                                                   args, 0, stream);
        if (le != hipSuccess) { (void)hipGetLastError(); coop = false; }
    }
    if (!coop) {
        for (int t = 0; t < NT; ++t) {
            hipLaunchKernelGGL(lif_step, dim3(NB * NC / 4), dim3(256), 0, stream,
                               x, out, t);
            if (t < NT - 1)
                hipLaunchKernelGGL(lif_mlp, dim3(NB), dim3(64), 0, stream,
                                   w1, b1, w2, b2);
        }
    }
}

// Round 6
// 296.915 us; speedup vs baseline: 1.2698x; 1.2698x over previous
//
#include <hip/hip_runtime.h>

typedef float v4f __attribute__((ext_vector_type(4)));

#define NB   32     // batch
#define NT   8      // timesteps
#define NC   128    // channels
#define NQ   256    // float4s per (H*W)=1024 plane
#define CRED 32     // C/red
#define PADI 32     // ints of padding per arrival counter (128 B line)

// Cross-block state in device globals. ALL cross-block traffic goes through
// relaxed agent-scope atomics (LLC-direct, bypassing L1/L2), so no
// release/acquire fences -> no cache-maintenance storms. Plain (non-
// cooperative) launch: 1024 blocks @ 56 VGPR = 4 blocks/CU out of 8 capacity,
// so all blocks are co-resident and the per-batch spin barrier cannot
// deadlock. (R5 showed coop-launch protocol overhead ~250 us/replay.)
__device__ int                g_arrive[NB * PADI];      // per-batch arrival counters
__device__ unsigned long long g_xsum[2 * NB * NC];      // double-buffered mean bits

__global__ __launch_bounds__(256)
void lif_init() {
    int i = threadIdx.x + blockIdx.x * blockDim.x;
    if (i < NB * PADI) g_arrive[i] = 0;
}

// ---------------------------------------------------------------------------
// Single persistent kernel, plain launch. 1024 blocks (one per (b, 4-channel
// group)), 256 threads; mem state in registers. Per step: fused
// fma/spike/reset/store + plane-mean publish (LLC atomics), per-batch
// 32-arrival barrier (relaxed atomics, NO fences), then each block
// redundantly computes its batch's 128->32->1 MLP for the next tau.
// ---------------------------------------------------------------------------
__global__ __launch_bounds__(256, 4)
void dynamic_lif(const float* __restrict__ x,
                 const float* __restrict__ w1,
                 const float* __restrict__ b1,
                 const float* __restrict__ w2,
                 const float* __restrict__ b2,
                 float* __restrict__ out)
{
    const int bid = blockIdx.x;          // 0..1023
    const int b   = bid >> 5;            // batch
    const int c0  = (bid & 31) << 2;     // first of 4 channels
    const int tid = threadIdx.x;
    const int wv  = tid >> 6;
    const int ln  = tid & 63;

    __shared__ double s_part[4][4];
    __shared__ float  s_tau;

    const v4f* __restrict__ x4 = (const v4f*)x;
    v4f* __restrict__ o4       = (v4f*)out;

    v4f mem[4];
    #pragma unroll
    for (int p = 0; p < 4; ++p) mem[p] = (v4f){0.f, 0.f, 0.f, 0.f};

    float tau = 0.5f;                    // TAU0

    v4f xv[4];
    #pragma unroll
    for (int p = 0; p < 4; ++p)
        xv[p] = __builtin_nontemporal_load(x4 + ((b * NT + 0) * NC + c0 + p) * NQ + tid);

    for (int t = 0; t < NT; ++t) {
        double psum[4];
        #pragma unroll
        for (int p = 0; p < 4; ++p) {
            v4f m = mem[p];
            m.x = fmaf(m.x, tau, xv[p].x);
            m.y = fmaf(m.y, tau, xv[p].y);
            m.z = fmaf(m.z, tau, xv[p].z);
            m.w = fmaf(m.w, tau, xv[p].w);
            psum[p] = ((double)m.x + (double)m.y) + ((double)m.z + (double)m.w);
            v4f sp;
            sp.x = (m.x > 1.0f) ? 1.0f : 0.0f;   // zif(mem-1): exact (Sterbenz)
            sp.y = (m.y > 1.0f) ? 1.0f : 0.0f;
            sp.z = (m.z > 1.0f) ? 1.0f : 0.0f;
            sp.w = (m.w > 1.0f) ? 1.0f : 0.0f;
            __builtin_nontemporal_store(sp, o4 + ((b * NT + t) * NC + c0 + p) * NQ + tid);
            m.x = (m.x > 1.0f) ? 0.0f : m.x;     // (1-spike)*mem
            m.y = (m.y > 1.0f) ? 0.0f : m.y;
            m.z = (m.z > 1.0f) ? 0.0f : m.z;
            m.w = (m.w > 1.0f) ? 0.0f : m.w;
            mem[p] = m;
        }

        // prefetch next x so the loads fly across the reduce + barrier
        if (t + 1 < NT) {
            #pragma unroll
            for (int p = 0; p < 4; ++p)
                xv[p] = __builtin_nontemporal_load(
                    x4 + ((b * NT + (t + 1)) * NC + c0 + p) * NQ + tid);
        }

        #pragma unroll
        for (int p = 0; p < 4; ++p) {
            double s = psum[p];
            #pragma unroll
            for (int off = 32; off > 0; off >>= 1) s += __shfl_down(s, off);
            if (ln == 0) s_part[p][wv] = s;
        }
        __syncthreads();
        if (tid < 4) {
            double s = (s_part[tid][0] + s_part[tid][1]) +
                       (s_part[tid][2] + s_part[tid][3]);
            double mean = s * (1.0 / 1024.0);
            unsigned long long bits = __double_as_longlong(mean);
            // LLC-direct publish: no fence needed, bypasses L1/L2
            __hip_atomic_store(&g_xsum[(t & 1) * (NB * NC) + b * NC + c0 + tid],
                               bits, __ATOMIC_RELAXED, __HIP_MEMORY_SCOPE_AGENT);
        }
        __syncthreads();   // s_waitcnt vmcnt(0): xsum stores committed at LLC

        if (t == NT - 1) break;

        // ---- per-batch barrier: relaxed LLC atomics only, zero fences ----
        if (tid == 0) {
            __hip_atomic_fetch_add(&g_arrive[b * PADI], 1,
                                   __ATOMIC_RELAXED, __HIP_MEMORY_SCOPE_AGENT);
            const int target = 32 * (t + 1);     // monotonic; init kernel zeroes
            while (__hip_atomic_load(&g_arrive[b * PADI],
                                     __ATOMIC_RELAXED, __HIP_MEMORY_SCOPE_AGENT) < target)
                __builtin_amdgcn_s_sleep(2);
        }
        __syncthreads();

        // tiny MLP (128->32->1), recomputed per block for its own batch.
        // xm via LLC-direct atomic loads (cannot be stale); w1 stays cached.
        double e = 0.0;
        if (tid < CRED) {
            const unsigned long long* __restrict__ xm =
                g_xsum + (t & 1) * (NB * NC) + b * NC;
            const float* __restrict__ w1r = w1 + tid * NC;
            double acc = (double)b1[tid];
            #pragma unroll 8
            for (int cc = 0; cc < NC; ++cc) {
                unsigned long long mb =
                    __hip_atomic_load(&xm[cc], __ATOMIC_RELAXED,
                                      __HIP_MEMORY_SCOPE_AGENT);
                acc += __longlong_as_double(mb) * (double)w1r[cc];
            }
            double emb = acc > 0.0 ? acc : 0.0;
            e = emb * (double)w2[tid];
        }
        #pragma unroll
        for (int off = 32; off > 0; off >>= 1) e += __shfl_down(e, off);
        if (tid == 0) {
            double z = e + (double)b2[0];
            s_tau = (float)(1.0 / (1.0 + exp(-z)));
        }
        __syncthreads();
        tau = s_tau;
    }
}

extern "C" void kernel_launch(void* const* d_in, const int* in_sizes, int n_in,
                              void* d_out, int out_size, void* d_ws, size_t ws_size,
                              hipStream_t stream) {
    const float* x  = (const float*)d_in[0];
    const float* w1 = (const float*)d_in[1];
    const float* b1 = (const float*)d_in[2];
    const float* w2 = (const float*)d_in[3];
    const float* b2 = (const float*)d_in[4];
    float* out      = (float*)d_out;

    // zero the arrival counters (stream-ordered before the main kernel)
    hipLaunchKernelGGL(lif_init, dim3((NB * PADI + 255) / 256), dim3(256),
                       0, stream);
    // plain launch — no cooperative protocol overhead
    hipLaunchKernelGGL(dynamic_lif, dim3(NB * NC / 4), dim3(256), 0, stream,
                       x, w1, b1, w2, b2, out);
}